// Round 1
// baseline (1025.094 us; speedup 1.0000x reference)
//
#include <hip/hip_runtime.h>

#define B_ 16
#define C_ 256
#define T_ 2048
#define K_TOP 256

// ---------------------------------------------------------------------------
// K1: inverse column norms  invn[b,t] = 1 / max(||x[b,:,t]||, 1e-12)
// ---------------------------------------------------------------------------
__global__ __launch_bounds__(256) void norm_kernel(const float* __restrict__ x,
                                                   float* __restrict__ invn) {
    const int b = blockIdx.y;
    const int t = blockIdx.x * 256 + threadIdx.x;
    const float* xp = x + (size_t)b * C_ * T_ + t;
    float acc = 0.f;
#pragma unroll 8
    for (int c = 0; c < C_; ++c) {
        float v = xp[(size_t)c * T_];
        acc = fmaf(v, v, acc);
    }
    invn[b * T_ + t] = 1.0f / fmaxf(sqrtf(acc), 1e-12f);
}

// ---------------------------------------------------------------------------
// K2: sim[b,t,s] = invn[t]*invn[s] * sum_c x[b,c,t]*x[b,c,s]
// 128x128 tile per block, 256 threads, 8x8 microtile (2x2 quadrants of 4)
// ---------------------------------------------------------------------------
__global__ __launch_bounds__(256) void sim_kernel(const float* __restrict__ x,
                                                  const float* __restrict__ invn,
                                                  float* __restrict__ sim) {
    const int b  = blockIdx.z;
    const int t0 = blockIdx.y * 128;
    const int s0 = blockIdx.x * 128;
    const float* X = x + (size_t)b * C_ * T_;

    __shared__ float As[8][128];   // As[k][m] = X[k0+k][t0+m]
    __shared__ float Bs[8][128];   // Bs[k][n] = X[k0+k][s0+n]

    const int tid  = threadIdx.x;
    const int lrow = tid >> 5;          // 0..7
    const int lcol = (tid & 31) << 2;   // 0..124
    const int m4   = (tid & 15) << 2;   // quadrant base (m)
    const int n4   = (tid >> 4) << 2;   // quadrant base (n)

    float acc[8][8];
#pragma unroll
    for (int i = 0; i < 8; ++i)
#pragma unroll
        for (int j = 0; j < 8; ++j) acc[i][j] = 0.f;

    for (int k0 = 0; k0 < C_; k0 += 8) {
        const float4 a4 = *(const float4*)(X + (size_t)(k0 + lrow) * T_ + t0 + lcol);
        const float4 b4 = *(const float4*)(X + (size_t)(k0 + lrow) * T_ + s0 + lcol);
        __syncthreads();
        *(float4*)&As[lrow][lcol] = a4;
        *(float4*)&Bs[lrow][lcol] = b4;
        __syncthreads();
#pragma unroll
        for (int k = 0; k < 8; ++k) {
            float a[8], bb[8];
            *(float4*)(a)      = *(const float4*)&As[k][m4];
            *(float4*)(a + 4)  = *(const float4*)&As[k][m4 + 64];
            *(float4*)(bb)     = *(const float4*)&Bs[k][n4];
            *(float4*)(bb + 4) = *(const float4*)&Bs[k][n4 + 64];
#pragma unroll
            for (int i = 0; i < 8; ++i)
#pragma unroll
                for (int j = 0; j < 8; ++j)
                    acc[i][j] = fmaf(a[i], bb[j], acc[i][j]);
        }
    }

    const float* ivb = invn + b * T_;
    float it[8], is[8];
#pragma unroll
    for (int i = 0; i < 8; ++i) {
        int mi = (i < 4) ? (m4 + i) : (64 + m4 + i - 4);
        int ni = (i < 4) ? (n4 + i) : (64 + n4 + i - 4);
        it[i] = ivb[t0 + mi];
        is[i] = ivb[s0 + ni];
    }
#pragma unroll
    for (int i = 0; i < 8; ++i) {
        int mi = (i < 4) ? (m4 + i) : (64 + m4 + i - 4);
        float* dst = sim + ((size_t)(b * T_ + t0 + mi)) * T_ + s0;
        float4 w0, w1;
        w0.x = acc[i][0] * it[i] * is[0];
        w0.y = acc[i][1] * it[i] * is[1];
        w0.z = acc[i][2] * it[i] * is[2];
        w0.w = acc[i][3] * it[i] * is[3];
        w1.x = acc[i][4] * it[i] * is[4];
        w1.y = acc[i][5] * it[i] * is[5];
        w1.z = acc[i][6] * it[i] * is[6];
        w1.w = acc[i][7] * it[i] * is[7];
        *(float4*)(dst + n4)      = w0;
        *(float4*)(dst + n4 + 64) = w1;
    }
}

// ---------------------------------------------------------------------------
// K3: per-row exact k-th largest (k=256) via 4-round MSB radix select on
// order-preserving uint keys; then sum of kept values. One block per row.
// ---------------------------------------------------------------------------
__global__ __launch_bounds__(256) void select_kernel(const float* __restrict__ sim,
                                                     float* __restrict__ cutoff,
                                                     float* __restrict__ isum) {
    const int row = blockIdx.x;                 // b*T + t
    const float* srow = sim + (size_t)row * T_;
    __shared__ float vals[T_];
    __shared__ int hist[256];
    __shared__ int scan[256];
    __shared__ int sel_b, sel_kk;
    const int tid = threadIdx.x;

#pragma unroll
    for (int j = 0; j < 8; ++j) vals[j * 256 + tid] = srow[j * 256 + tid];
    __syncthreads();

    unsigned prefix = 0;
    int kk = K_TOP;

    for (int shift = 24; shift >= 0; shift -= 8) {
        hist[tid] = 0;
        __syncthreads();
#pragma unroll
        for (int j = 0; j < 8; ++j) {
            unsigned u = __float_as_uint(vals[j * 256 + tid]);
            unsigned key = (u & 0x80000000u) ? ~u : (u ^ 0x80000000u);
            bool active = (shift == 24) || ((key >> (shift + 8)) == prefix);
            if (active) atomicAdd(&hist[(key >> shift) & 255], 1);
        }
        __syncthreads();
        // suffix counts: scan[i] = #elements with byte >= (255-i)
        scan[tid] = hist[255 - tid];
        __syncthreads();
        for (int off = 1; off < 256; off <<= 1) {
            int v = scan[tid];
            int add = (tid >= off) ? scan[tid - off] : 0;
            __syncthreads();
            scan[tid] = v + add;
            __syncthreads();
        }
        int S   = scan[tid];
        int Sm1 = (tid == 0) ? 0 : scan[tid - 1];
        if (S >= kk && Sm1 < kk) {
            sel_b  = 255 - tid;
            sel_kk = kk - Sm1;
        }
        __syncthreads();
        prefix = (prefix << 8) | (unsigned)sel_b;
        kk = sel_kk;
        __syncthreads();
    }

    // invert the key transform -> cutoff value (exact k-th largest)
    unsigned u = (prefix & 0x80000000u) ? (prefix ^ 0x80000000u) : ~prefix;
    const float cut = __uint_as_float(u);

    float s = 0.f;
#pragma unroll
    for (int j = 0; j < 8; ++j) {
        float v = vals[j * 256 + tid];
        if (v >= cut) s += v;
    }
#pragma unroll
    for (int off = 32; off > 0; off >>= 1) s += __shfl_down(s, off);
    __shared__ float partial[4];
    if ((tid & 63) == 0) partial[tid >> 6] = s;
    __syncthreads();
    if (tid == 0) {
        float tot = partial[0] + partial[1] + partial[2] + partial[3];
        if (tot == 0.f) tot = 1.f;
        cutoff[row] = cut;
        isum[row]   = 1.0f / tot;
    }
}

// ---------------------------------------------------------------------------
// K4: out0[b,c,t] = x[b,c,t] + sum_s w[t,s]*x[b,c,s]
//     w[t,s] = (sim[t,s] >= cutoff[t]) ? sim[t,s]*isum[t] : 0
// M=c (tiles of 128), N=t (tiles of 128), K=s
// ---------------------------------------------------------------------------
__global__ __launch_bounds__(256) void out_kernel(const float* __restrict__ x,
                                                  const float* __restrict__ sim,
                                                  const float* __restrict__ cutoff,
                                                  const float* __restrict__ isum,
                                                  float* __restrict__ out0) {
    const int b  = blockIdx.z;
    const int c0 = blockIdx.y * 128;
    const int t0 = blockIdx.x * 128;
    const float* X = x   + (size_t)b * C_ * T_;
    const float* S = sim + (size_t)b * T_ * T_;

    __shared__ float As[8][128];   // As[k][m] = X[c0+m][k0+k]
    __shared__ float Bs[8][128];   // Bs[k][n] = w[t0+n][k0+k]

    const int tid  = threadIdx.x;
    const int arow = tid >> 1;          // 0..127
    const int acol = (tid & 1) << 2;    // 0 or 4
    const int m4   = (tid & 15) << 2;
    const int n4   = (tid >> 4) << 2;

    const float cutv = cutoff[b * T_ + t0 + arow];
    const float isv  = isum  [b * T_ + t0 + arow];

    float acc[8][8];
#pragma unroll
    for (int i = 0; i < 8; ++i)
#pragma unroll
        for (int j = 0; j < 8; ++j) acc[i][j] = 0.f;

    for (int k0 = 0; k0 < T_; k0 += 8) {
        const float4 a4 = *(const float4*)(X + (size_t)(c0 + arow) * T_ + k0 + acol);
        float4 s4 = *(const float4*)(S + (size_t)(t0 + arow) * T_ + k0 + acol);
        s4.x = (s4.x >= cutv) ? s4.x * isv : 0.f;
        s4.y = (s4.y >= cutv) ? s4.y * isv : 0.f;
        s4.z = (s4.z >= cutv) ? s4.z * isv : 0.f;
        s4.w = (s4.w >= cutv) ? s4.w * isv : 0.f;
        __syncthreads();
        As[acol + 0][arow] = a4.x;
        As[acol + 1][arow] = a4.y;
        As[acol + 2][arow] = a4.z;
        As[acol + 3][arow] = a4.w;
        Bs[acol + 0][arow] = s4.x;
        Bs[acol + 1][arow] = s4.y;
        Bs[acol + 2][arow] = s4.z;
        Bs[acol + 3][arow] = s4.w;
        __syncthreads();
#pragma unroll
        for (int k = 0; k < 8; ++k) {
            float a[8], bb[8];
            *(float4*)(a)      = *(const float4*)&As[k][m4];
            *(float4*)(a + 4)  = *(const float4*)&As[k][m4 + 64];
            *(float4*)(bb)     = *(const float4*)&Bs[k][n4];
            *(float4*)(bb + 4) = *(const float4*)&Bs[k][n4 + 64];
#pragma unroll
            for (int i = 0; i < 8; ++i)
#pragma unroll
                for (int j = 0; j < 8; ++j)
                    acc[i][j] = fmaf(a[i], bb[j], acc[i][j]);
        }
    }

#pragma unroll
    for (int i = 0; i < 8; ++i) {
        int mi = (i < 4) ? (m4 + i) : (64 + m4 + i - 4);
        const float* xrow = X + (size_t)(c0 + mi) * T_ + t0;
        float* dst = out0 + (size_t)(b * C_ + c0 + mi) * T_ + t0;
        float4 x0 = *(const float4*)(xrow + n4);
        float4 x1 = *(const float4*)(xrow + n4 + 64);
        float4 w0, w1;
        w0.x = acc[i][0] + x0.x;
        w0.y = acc[i][1] + x0.y;
        w0.z = acc[i][2] + x0.z;
        w0.w = acc[i][3] + x0.w;
        w1.x = acc[i][4] + x1.x;
        w1.y = acc[i][5] + x1.y;
        w1.z = acc[i][6] + x1.z;
        w1.w = acc[i][7] + x1.w;
        *(float4*)(dst + n4)      = w0;
        *(float4*)(dst + n4 + 64) = w1;
    }
}

// ---------------------------------------------------------------------------
extern "C" void kernel_launch(void* const* d_in, const int* in_sizes, int n_in,
                              void* d_out, int out_size, void* d_ws, size_t ws_size,
                              hipStream_t stream) {
    const float* x = (const float*)d_in[0];
    float* out0 = (float*)d_out;                              // (B,C,T)
    float* sim  = out0 + (size_t)B_ * C_ * T_;                // (B,T,T)

    float* invn   = (float*)d_ws;                             // B*T
    float* cutoff = invn + B_ * T_;                           // B*T
    float* isv    = cutoff + B_ * T_;                         // B*T

    norm_kernel  <<<dim3(T_ / 256, B_),        256, 0, stream>>>(x, invn);
    sim_kernel   <<<dim3(T_ / 128, T_ / 128, B_), 256, 0, stream>>>(x, invn, sim);
    select_kernel<<<dim3(B_ * T_),             256, 0, stream>>>(sim, cutoff, isv);
    out_kernel   <<<dim3(T_ / 128, C_ / 128, B_), 256, 0, stream>>>(x, sim, cutoff, isv, out0);
}

// Round 2
// 405.587 us; speedup vs baseline: 2.5274x; 2.5274x over previous
//
#include <hip/hip_runtime.h>

#define B_ 16
#define C_ 256
#define T_ 2048
#define K_TOP 256

typedef float  f32x4 __attribute__((ext_vector_type(4)));
typedef short  s16x8 __attribute__((ext_vector_type(8)));

static inline __device__ ushort f2bf(float f) {
    unsigned u = __float_as_uint(f);
    u += 0x7FFF + ((u >> 16) & 1);          // round-to-nearest-even
    return (ushort)(u >> 16);
}

// ---------------------------------------------------------------------------
// K1: inverse column norms  invn[b,t] = 1 / max(||x[b,:,t]||, 1e-12)
// ---------------------------------------------------------------------------
__global__ __launch_bounds__(256) void norm_kernel(const float* __restrict__ x,
                                                   float* __restrict__ invn) {
    const int b = blockIdx.y;
    const int t = blockIdx.x * 256 + threadIdx.x;
    const float* xp = x + (size_t)b * C_ * T_ + t;
    float acc = 0.f;
#pragma unroll 8
    for (int c = 0; c < C_; ++c) {
        float v = xp[(size_t)c * T_];
        acc = fmaf(v, v, acc);
    }
    invn[b * T_ + t] = 1.0f / fmaxf(sqrtf(acc), 1e-12f);
}

// ---------------------------------------------------------------------------
// K1b: xt[b][t][c] = bf16( x[b][c][t] * invn[b][t] )   (transpose + normalize)
// 64x64 tiles via LDS
// ---------------------------------------------------------------------------
__global__ __launch_bounds__(256) void xt_kernel(const float* __restrict__ x,
                                                 const float* __restrict__ invn,
                                                 ushort* __restrict__ xt) {
    const int b  = blockIdx.z;
    const int c0 = blockIdx.y * 64;
    const int t0 = blockIdx.x * 64;
    const float* Xb = x + (size_t)b * C_ * T_;
    ushort* Ob = xt + (size_t)b * T_ * C_;
    __shared__ float tile[64][65];
    const int tid = threadIdx.x;

#pragma unroll
    for (int it = 0; it < 4; ++it) {
        int ch = tid + it * 256;
        int r  = ch >> 4;            // c index 0..63
        int c4 = (ch & 15) << 2;     // t index 0..60
        float4 v = *(const float4*)(Xb + (size_t)(c0 + r) * T_ + t0 + c4);
        tile[r][c4 + 0] = v.x;
        tile[r][c4 + 1] = v.y;
        tile[r][c4 + 2] = v.z;
        tile[r][c4 + 3] = v.w;
    }
    __syncthreads();
#pragma unroll
    for (int it = 0; it < 4; ++it) {
        int ch = tid + it * 256;
        int r2  = ch >> 4;           // t index 0..63
        int cc4 = (ch & 15) << 2;    // c index 0..60
        float sc = invn[b * T_ + t0 + r2];
        ushort4 w;
        w.x = f2bf(tile[cc4 + 0][r2] * sc);
        w.y = f2bf(tile[cc4 + 1][r2] * sc);
        w.z = f2bf(tile[cc4 + 2][r2] * sc);
        w.w = f2bf(tile[cc4 + 3][r2] * sc);
        *(ushort4*)(Ob + (size_t)(t0 + r2) * C_ + c0 + cc4) = w;
    }
}

// ---------------------------------------------------------------------------
// K2: sim[b,t,s] = sum_c xt[t][c]*xt[s][c]   (bf16 MFMA, 128x128 tile)
// 4 waves; each wave: 64x64 (4x4 frags of 16x16x32); BK=64; LDS stride 72
// ---------------------------------------------------------------------------
__global__ __launch_bounds__(256) void sim_mfma(const ushort* __restrict__ xt,
                                                float* __restrict__ sim) {
    const int b  = blockIdx.z;
    const int t0 = blockIdx.y * 128;
    const int s0 = blockIdx.x * 128;
    const ushort* Xb = xt + (size_t)b * T_ * C_;

    __shared__ ushort Al[128 * 72];
    __shared__ ushort Bl[128 * 72];

    const int tid  = threadIdx.x;
    const int lane = tid & 63;
    const int wv   = tid >> 6;
    const int wr   = (wv >> 1) * 64;
    const int wc   = (wv & 1) * 64;
    const int lr   = lane & 15;
    const int lg   = lane >> 4;

    f32x4 acc[4][4] = {};

    for (int k0 = 0; k0 < C_; k0 += 64) {
        __syncthreads();
#pragma unroll
        for (int it = 0; it < 4; ++it) {
            int ch = tid + it * 256;
            int r  = ch >> 3;
            int c8 = (ch & 7) << 3;
            s16x8 va = *(const s16x8*)(Xb + (size_t)(t0 + r) * C_ + k0 + c8);
            *(s16x8*)&Al[r * 72 + c8] = va;
            s16x8 vb = *(const s16x8*)(Xb + (size_t)(s0 + r) * C_ + k0 + c8);
            *(s16x8*)&Bl[r * 72 + c8] = vb;
        }
        __syncthreads();
#pragma unroll
        for (int kk = 0; kk < 2; ++kk) {
            s16x8 af[4], bf[4];
#pragma unroll
            for (int i = 0; i < 4; ++i)
                af[i] = *(const s16x8*)&Al[(wr + i * 16 + lr) * 72 + kk * 32 + lg * 8];
#pragma unroll
            for (int j = 0; j < 4; ++j)
                bf[j] = *(const s16x8*)&Bl[(wc + j * 16 + lr) * 72 + kk * 32 + lg * 8];
#pragma unroll
            for (int i = 0; i < 4; ++i)
#pragma unroll
                for (int j = 0; j < 4; ++j)
                    acc[i][j] = __builtin_amdgcn_mfma_f32_16x16x32_bf16(af[i], bf[j], acc[i][j], 0, 0, 0);
        }
    }

    float* Sb = sim + (size_t)b * T_ * T_;
#pragma unroll
    for (int i = 0; i < 4; ++i)
#pragma unroll
        for (int j = 0; j < 4; ++j)
#pragma unroll
            for (int reg = 0; reg < 4; ++reg) {
                int t = t0 + wr + i * 16 + lg * 4 + reg;
                int s = s0 + wc + j * 16 + lr;
                Sb[(size_t)t * T_ + s] = acc[i][j][reg];
            }
}

// ---------------------------------------------------------------------------
// K3: per-row exact k-th largest (k=256) via 4-round MSB radix select
// ---------------------------------------------------------------------------
__global__ __launch_bounds__(256) void select_kernel(const float* __restrict__ sim,
                                                     float* __restrict__ cutoff,
                                                     float* __restrict__ isum) {
    const int row = blockIdx.x;                 // b*T + t
    const float* srow = sim + (size_t)row * T_;
    __shared__ float vals[T_];
    __shared__ int hist[256];
    __shared__ int scan[256];
    __shared__ int sel_b, sel_kk;
    const int tid = threadIdx.x;

#pragma unroll
    for (int j = 0; j < 2; ++j)
        ((float4*)vals)[tid + j * 256] = ((const float4*)srow)[tid + j * 256];
    __syncthreads();

    unsigned prefix = 0;
    int kk = K_TOP;

    for (int shift = 24; shift >= 0; shift -= 8) {
        hist[tid] = 0;
        __syncthreads();
#pragma unroll
        for (int j = 0; j < 8; ++j) {
            unsigned u = __float_as_uint(vals[j * 256 + tid]);
            unsigned key = (u & 0x80000000u) ? ~u : (u ^ 0x80000000u);
            bool active = (shift == 24) || ((key >> (shift + 8)) == prefix);
            if (active) atomicAdd(&hist[(key >> shift) & 255], 1);
        }
        __syncthreads();
        scan[tid] = hist[255 - tid];
        __syncthreads();
        for (int off = 1; off < 256; off <<= 1) {
            int v = scan[tid];
            int add = (tid >= off) ? scan[tid - off] : 0;
            __syncthreads();
            scan[tid] = v + add;
            __syncthreads();
        }
        int S   = scan[tid];
        int Sm1 = (tid == 0) ? 0 : scan[tid - 1];
        if (S >= kk && Sm1 < kk) {
            sel_b  = 255 - tid;
            sel_kk = kk - Sm1;
        }
        __syncthreads();
        prefix = (prefix << 8) | (unsigned)sel_b;
        kk = sel_kk;
        __syncthreads();
    }

    unsigned u = (prefix & 0x80000000u) ? (prefix ^ 0x80000000u) : ~prefix;
    const float cut = __uint_as_float(u);

    float s = 0.f;
#pragma unroll
    for (int j = 0; j < 8; ++j) {
        float v = vals[j * 256 + tid];
        if (v >= cut) s += v;
    }
#pragma unroll
    for (int off = 32; off > 0; off >>= 1) s += __shfl_down(s, off);
    __shared__ float partial[4];
    if ((tid & 63) == 0) partial[tid >> 6] = s;
    __syncthreads();
    if (tid == 0) {
        float tot = partial[0] + partial[1] + partial[2] + partial[3];
        if (tot == 0.f) tot = 1.f;
        cutoff[row] = cut;
        isum[row]   = 1.0f / tot;
    }
}

// ---------------------------------------------------------------------------
// K4: out0[b,c,t] = x[b,c,t] + sum_s w[t,s]*x[b,c,s]  (bf16 MFMA)
//     w[t,s] = (sim[t,s] >= cutoff[t]) ? sim[t,s]*isum[t] : 0
// M=c(128), N=t(128), K=s(2048, BK=64)
// ---------------------------------------------------------------------------
__global__ __launch_bounds__(256) void out_mfma(const float* __restrict__ x,
                                                const float* __restrict__ sim,
                                                const float* __restrict__ cutoff,
                                                const float* __restrict__ isum,
                                                float* __restrict__ out0) {
    const int b  = blockIdx.z;
    const int c0 = blockIdx.y * 128;
    const int t0 = blockIdx.x * 128;
    const float* Xb = x   + (size_t)b * C_ * T_;
    const float* Sb = sim + (size_t)b * T_ * T_;

    __shared__ ushort Al[128 * 72];
    __shared__ ushort Bl[128 * 72];
    __shared__ float cut_l[128];
    __shared__ float isv_l[128];

    const int tid  = threadIdx.x;
    const int lane = tid & 63;
    const int wv   = tid >> 6;
    const int wr   = (wv >> 1) * 64;
    const int wc   = (wv & 1) * 64;
    const int lr   = lane & 15;
    const int lg   = lane >> 4;

    if (tid < 128) {
        cut_l[tid] = cutoff[b * T_ + t0 + tid];
        isv_l[tid] = isum  [b * T_ + t0 + tid];
    }

    f32x4 acc[4][4] = {};

    for (int k0 = 0; k0 < T_; k0 += 64) {
        __syncthreads();
#pragma unroll
        for (int it = 0; it < 4; ++it) {
            int ch = tid + it * 256;
            int r  = ch >> 3;
            int c8 = (ch & 7) << 3;
            // A: x[c0+r][k0+c8 .. +7]
            const float4* pa = (const float4*)(Xb + (size_t)(c0 + r) * T_ + k0 + c8);
            float4 a0 = pa[0], a1 = pa[1];
            ushort aw[8];
            aw[0]=f2bf(a0.x); aw[1]=f2bf(a0.y); aw[2]=f2bf(a0.z); aw[3]=f2bf(a0.w);
            aw[4]=f2bf(a1.x); aw[5]=f2bf(a1.y); aw[6]=f2bf(a1.z); aw[7]=f2bf(a1.w);
            *(s16x8*)&Al[r * 72 + c8] = *(const s16x8*)aw;
            // B: w[t0+r][k0+c8 .. +7]
            const float4* pb = (const float4*)(Sb + (size_t)(t0 + r) * T_ + k0 + c8);
            float4 b0 = pb[0], b1 = pb[1];
            float cut = cut_l[r], sc = isv_l[r];
            ushort bw[8];
            bw[0]=f2bf(b0.x >= cut ? b0.x * sc : 0.f);
            bw[1]=f2bf(b0.y >= cut ? b0.y * sc : 0.f);
            bw[2]=f2bf(b0.z >= cut ? b0.z * sc : 0.f);
            bw[3]=f2bf(b0.w >= cut ? b0.w * sc : 0.f);
            bw[4]=f2bf(b1.x >= cut ? b1.x * sc : 0.f);
            bw[5]=f2bf(b1.y >= cut ? b1.y * sc : 0.f);
            bw[6]=f2bf(b1.z >= cut ? b1.z * sc : 0.f);
            bw[7]=f2bf(b1.w >= cut ? b1.w * sc : 0.f);
            *(s16x8*)&Bl[r * 72 + c8] = *(const s16x8*)bw;
        }
        __syncthreads();
#pragma unroll
        for (int kk = 0; kk < 2; ++kk) {
            s16x8 af[4], bf[4];
#pragma unroll
            for (int i = 0; i < 4; ++i)
                af[i] = *(const s16x8*)&Al[(wr + i * 16 + lr) * 72 + kk * 32 + lg * 8];
#pragma unroll
            for (int j = 0; j < 4; ++j)
                bf[j] = *(const s16x8*)&Bl[(wc + j * 16 + lr) * 72 + kk * 32 + lg * 8];
#pragma unroll
            for (int i = 0; i < 4; ++i)
#pragma unroll
                for (int j = 0; j < 4; ++j)
                    acc[i][j] = __builtin_amdgcn_mfma_f32_16x16x32_bf16(af[i], bf[j], acc[i][j], 0, 0, 0);
        }
    }

#pragma unroll
    for (int i = 0; i < 4; ++i)
#pragma unroll
        for (int j = 0; j < 4; ++j)
#pragma unroll
            for (int reg = 0; reg < 4; ++reg) {
                int c = c0 + wr + i * 16 + lg * 4 + reg;
                int t = t0 + wc + j * 16 + lr;
                out0[((size_t)(b * C_ + c)) * T_ + t] = acc[i][j][reg] + Xb[(size_t)c * T_ + t];
            }
}

// ---------------------------------------------------------------------------
extern "C" void kernel_launch(void* const* d_in, const int* in_sizes, int n_in,
                              void* d_out, int out_size, void* d_ws, size_t ws_size,
                              hipStream_t stream) {
    const float* x = (const float*)d_in[0];
    float* out0 = (float*)d_out;                              // (B,C,T)
    float* sim  = out0 + (size_t)B_ * C_ * T_;                // (B,T,T)

    // scratch: xt (bf16, B*T*C) lives in the out0 region until out_mfma runs
    ushort* xt = (ushort*)d_out;

    float* invn   = (float*)d_ws;                             // B*T
    float* cutoff = invn + B_ * T_;                           // B*T
    float* isv    = cutoff + B_ * T_;                         // B*T

    norm_kernel  <<<dim3(T_ / 256, B_),           256, 0, stream>>>(x, invn);
    xt_kernel    <<<dim3(T_ / 64, C_ / 64, B_),   256, 0, stream>>>(x, invn, xt);
    sim_mfma     <<<dim3(T_ / 128, T_ / 128, B_), 256, 0, stream>>>(xt, sim);
    select_kernel<<<dim3(B_ * T_),                256, 0, stream>>>(sim, cutoff, isv);
    out_mfma     <<<dim3(T_ / 128, C_ / 128, B_), 256, 0, stream>>>(x, sim, cutoff, isv, out0);
}

// Round 3
// 286.237 us; speedup vs baseline: 3.5813x; 1.4170x over previous
//
#include <hip/hip_runtime.h>

#define B_ 16
#define C_ 256
#define T_ 2048
#define K_TOP 256

typedef float  f32x4 __attribute__((ext_vector_type(4)));
typedef short  s16x8 __attribute__((ext_vector_type(8)));

static inline __device__ ushort f2bf(float f) {
    unsigned u = __float_as_uint(f);
    u += 0x7FFF + ((u >> 16) & 1);          // round-to-nearest-even
    return (ushort)(u >> 16);
}

static inline __device__ unsigned key_of(float f) {
    unsigned u = __float_as_uint(f);
    return (u & 0x80000000u) ? ~u : (u | 0x80000000u);   // order-preserving
}
static inline __device__ float val_of(unsigned k) {
    unsigned u = (k & 0x80000000u) ? (k ^ 0x80000000u) : ~k;
    return __uint_as_float(u);
}

// ---------------------------------------------------------------------------
// K1: inverse column norms  invn[b,t] = 1 / max(||x[b,:,t]||, 1e-12)
// ---------------------------------------------------------------------------
__global__ __launch_bounds__(256) void norm_kernel(const float* __restrict__ x,
                                                   float* __restrict__ invn) {
    const int b = blockIdx.y;
    const int t = blockIdx.x * 256 + threadIdx.x;
    const float* xp = x + (size_t)b * C_ * T_ + t;
    float acc = 0.f;
#pragma unroll 8
    for (int c = 0; c < C_; ++c) {
        float v = xp[(size_t)c * T_];
        acc = fmaf(v, v, acc);
    }
    invn[b * T_ + t] = 1.0f / fmaxf(sqrtf(acc), 1e-12f);
}

// ---------------------------------------------------------------------------
// K1b: xt[b][t][c] = bf16( x[b][c][t] * invn[b][t] )   (transpose + normalize)
// ---------------------------------------------------------------------------
__global__ __launch_bounds__(256) void xt_kernel(const float* __restrict__ x,
                                                 const float* __restrict__ invn,
                                                 ushort* __restrict__ xt) {
    const int b  = blockIdx.z;
    const int c0 = blockIdx.y * 64;
    const int t0 = blockIdx.x * 64;
    const float* Xb = x + (size_t)b * C_ * T_;
    ushort* Ob = xt + (size_t)b * T_ * C_;
    __shared__ float tile[64][65];
    const int tid = threadIdx.x;

#pragma unroll
    for (int it = 0; it < 4; ++it) {
        int ch = tid + it * 256;
        int r  = ch >> 4;
        int c4 = (ch & 15) << 2;
        float4 v = *(const float4*)(Xb + (size_t)(c0 + r) * T_ + t0 + c4);
        tile[r][c4 + 0] = v.x;
        tile[r][c4 + 1] = v.y;
        tile[r][c4 + 2] = v.z;
        tile[r][c4 + 3] = v.w;
    }
    __syncthreads();
#pragma unroll
    for (int it = 0; it < 4; ++it) {
        int ch = tid + it * 256;
        int r2  = ch >> 4;
        int cc4 = (ch & 15) << 2;
        float sc = invn[b * T_ + t0 + r2];
        ushort4 w;
        w.x = f2bf(tile[cc4 + 0][r2] * sc);
        w.y = f2bf(tile[cc4 + 1][r2] * sc);
        w.z = f2bf(tile[cc4 + 2][r2] * sc);
        w.w = f2bf(tile[cc4 + 3][r2] * sc);
        *(ushort4*)(Ob + (size_t)(t0 + r2) * C_ + c0 + cc4) = w;
    }
}

// ---------------------------------------------------------------------------
// K2: sim[b,t,s] = sum_c xt[t][c]*xt[s][c]   (bf16 MFMA, 128x128 tile)
// ---------------------------------------------------------------------------
__global__ __launch_bounds__(256) void sim_mfma(const ushort* __restrict__ xt,
                                                float* __restrict__ sim) {
    const int b  = blockIdx.z;
    const int t0 = blockIdx.y * 128;
    const int s0 = blockIdx.x * 128;
    const ushort* Xb = xt + (size_t)b * T_ * C_;

    __shared__ ushort Al[128 * 72];
    __shared__ ushort Bl[128 * 72];

    const int tid  = threadIdx.x;
    const int lane = tid & 63;
    const int wv   = tid >> 6;
    const int wr   = (wv >> 1) * 64;
    const int wc   = (wv & 1) * 64;
    const int lr   = lane & 15;
    const int lg   = lane >> 4;

    f32x4 acc[4][4] = {};

    for (int k0 = 0; k0 < C_; k0 += 64) {
        __syncthreads();
#pragma unroll
        for (int it = 0; it < 4; ++it) {
            int ch = tid + it * 256;
            int r  = ch >> 3;
            int c8 = (ch & 7) << 3;
            s16x8 va = *(const s16x8*)(Xb + (size_t)(t0 + r) * C_ + k0 + c8);
            *(s16x8*)&Al[r * 72 + c8] = va;
            s16x8 vb = *(const s16x8*)(Xb + (size_t)(s0 + r) * C_ + k0 + c8);
            *(s16x8*)&Bl[r * 72 + c8] = vb;
        }
        __syncthreads();
#pragma unroll
        for (int kk = 0; kk < 2; ++kk) {
            s16x8 af[4], bf[4];
#pragma unroll
            for (int i = 0; i < 4; ++i)
                af[i] = *(const s16x8*)&Al[(wr + i * 16 + lr) * 72 + kk * 32 + lg * 8];
#pragma unroll
            for (int j = 0; j < 4; ++j)
                bf[j] = *(const s16x8*)&Bl[(wc + j * 16 + lr) * 72 + kk * 32 + lg * 8];
#pragma unroll
            for (int i = 0; i < 4; ++i)
#pragma unroll
                for (int j = 0; j < 4; ++j)
                    acc[i][j] = __builtin_amdgcn_mfma_f32_16x16x32_bf16(af[i], bf[j], acc[i][j], 0, 0, 0);
        }
    }

    float* Sb = sim + (size_t)b * T_ * T_;
#pragma unroll
    for (int i = 0; i < 4; ++i)
#pragma unroll
        for (int j = 0; j < 4; ++j)
#pragma unroll
            for (int reg = 0; reg < 4; ++reg) {
                int t = t0 + wr + i * 16 + lg * 4 + reg;
                int s = s0 + wc + j * 16 + lr;
                Sb[(size_t)t * T_ + s] = acc[i][j][reg];
            }
}

// ---------------------------------------------------------------------------
// K3: per-row exact k-th largest (k=256), wave-per-row, registers + wave-
// private 4-copy interleaved LDS histogram. No __syncthreads anywhere.
// ---------------------------------------------------------------------------
__global__ __launch_bounds__(256) void select_kernel(const float* __restrict__ sim,
                                                     float* __restrict__ cutoff,
                                                     float* __restrict__ isum) {
    __shared__ int h_all[4][1024];   // per-wave: 256 bins x 4 interleaved copies
    __shared__ int m_all[4][256];    // per-wave: merged bins
    const int tid  = threadIdx.x;
    const int wv   = tid >> 6;
    const int lane = tid & 63;
    int* h = h_all[wv];
    int* m = m_all[wv];
    const int row = blockIdx.x * 4 + wv;
    const float* srow = sim + (size_t)row * T_;

    // load 2048 values -> 32 order-preserving keys per lane (coalesced)
    uint4 key[8];
#pragma unroll
    for (int j = 0; j < 8; ++j) {
        float4 v = ((const float4*)srow)[j * 64 + lane];
        key[j].x = key_of(v.x);
        key[j].y = key_of(v.y);
        key[j].z = key_of(v.z);
        key[j].w = key_of(v.w);
    }

    unsigned prefix = 0;
    int kk = K_TOP;

#pragma unroll
    for (int round = 0; round < 4; ++round) {
        const int shift = 24 - round * 8;
        // clear wave-private hist
        int4 z = {0, 0, 0, 0};
#pragma unroll
        for (int i = 0; i < 4; ++i) *(int4*)&h[i * 256 + (lane << 2)] = z;
        __builtin_amdgcn_wave_barrier();
        // count
        const int copy = lane & 3;
#pragma unroll
        for (int j = 0; j < 8; ++j) {
            const unsigned ks[4] = {key[j].x, key[j].y, key[j].z, key[j].w};
#pragma unroll
            for (int c = 0; c < 4; ++c) {
                unsigned ky = ks[c];
                bool active = (round == 0) || ((ky >> (shift + 8)) == prefix);
                if (active) atomicAdd(&h[(((ky >> shift) & 255) << 2) | copy], 1);
            }
        }
        __builtin_amdgcn_wave_barrier();
        // merge the 4 copies
#pragma unroll
        for (int i = 0; i < 4; ++i) {
            int4 hv = *(const int4*)&h[(i * 64 + lane) << 2];
            m[i * 64 + lane] = hv.x + hv.y + hv.z + hv.w;
        }
        __builtin_amdgcn_wave_barrier();
        // lane l owns bins [4l .. 4l+3]; suffix counts over lanes
        int4 mv = *(const int4*)&m[lane << 2];
        int cnt = mv.x + mv.y + mv.z + mv.w;
        int sc = __shfl(cnt, 63 - lane);         // reverse
#pragma unroll
        for (int off = 1; off < 64; off <<= 1) {
            int t = __shfl_up(sc, off);
            if (lane >= off) sc += t;
        }
        int S = __shfl(sc, 63 - lane);           // S_l = count with byte >= 4l
        int Sex = S - cnt;                       // count with byte >= 4l+4
        bool crossing = (S >= kk) && (Sex < kk);
        int sel = 0, kk2 = 0;
        if (crossing) {
            int rem = kk - Sex;                  // needed from this 4-bin group (top-down)
            int a3 = mv.w;
            int a2 = a3 + mv.z;
            int a1 = a2 + mv.y;
            if (rem <= a3)      { sel = 4 * lane + 3; kk2 = rem; }
            else if (rem <= a2) { sel = 4 * lane + 2; kk2 = rem - a3; }
            else if (rem <= a1) { sel = 4 * lane + 1; kk2 = rem - a2; }
            else                { sel = 4 * lane + 0; kk2 = rem - a1; }
        }
        unsigned long long bal = __ballot(crossing);
        int src = (int)(__ffsll((long long)bal) - 1);
        sel = __shfl(sel, src);
        kk2 = __shfl(kk2, src);
        prefix = (prefix << 8) | (unsigned)sel;
        kk = kk2;
    }

    const float cut = val_of(prefix);

    // sum of kept values
    float s = 0.f;
#pragma unroll
    for (int j = 0; j < 8; ++j) {
        const unsigned ks[4] = {key[j].x, key[j].y, key[j].z, key[j].w};
#pragma unroll
        for (int c = 0; c < 4; ++c)
            if (ks[c] >= prefix) s += val_of(ks[c]);
    }
#pragma unroll
    for (int off = 32; off > 0; off >>= 1) s += __shfl_down(s, off);
    if (lane == 0) {
        float tot = (s == 0.f) ? 1.f : s;
        cutoff[row] = cut;
        isum[row]   = 1.0f / tot;
    }
}

// ---------------------------------------------------------------------------
// K4: out0[b,c,t] = x[b,c,t] + sum_s w[t,s]*x[b,c,s]  (bf16 MFMA)
// ---------------------------------------------------------------------------
__global__ __launch_bounds__(256) void out_mfma(const float* __restrict__ x,
                                                const float* __restrict__ sim,
                                                const float* __restrict__ cutoff,
                                                const float* __restrict__ isum,
                                                float* __restrict__ out0) {
    const int b  = blockIdx.z;
    const int c0 = blockIdx.y * 128;
    const int t0 = blockIdx.x * 128;
    const float* Xb = x   + (size_t)b * C_ * T_;
    const float* Sb = sim + (size_t)b * T_ * T_;

    __shared__ ushort Al[128 * 72];
    __shared__ ushort Bl[128 * 72];
    __shared__ float cut_l[128];
    __shared__ float isv_l[128];

    const int tid  = threadIdx.x;
    const int lane = tid & 63;
    const int wv   = tid >> 6;
    const int wr   = (wv >> 1) * 64;
    const int wc   = (wv & 1) * 64;
    const int lr   = lane & 15;
    const int lg   = lane >> 4;

    if (tid < 128) {
        cut_l[tid] = cutoff[b * T_ + t0 + tid];
        isv_l[tid] = isum  [b * T_ + t0 + tid];
    }

    f32x4 acc[4][4] = {};

    for (int k0 = 0; k0 < T_; k0 += 64) {
        __syncthreads();
#pragma unroll
        for (int it = 0; it < 4; ++it) {
            int ch = tid + it * 256;
            int r  = ch >> 3;
            int c8 = (ch & 7) << 3;
            const float4* pa = (const float4*)(Xb + (size_t)(c0 + r) * T_ + k0 + c8);
            float4 a0 = pa[0], a1 = pa[1];
            ushort aw[8];
            aw[0]=f2bf(a0.x); aw[1]=f2bf(a0.y); aw[2]=f2bf(a0.z); aw[3]=f2bf(a0.w);
            aw[4]=f2bf(a1.x); aw[5]=f2bf(a1.y); aw[6]=f2bf(a1.z); aw[7]=f2bf(a1.w);
            *(s16x8*)&Al[r * 72 + c8] = *(const s16x8*)aw;
            const float4* pb = (const float4*)(Sb + (size_t)(t0 + r) * T_ + k0 + c8);
            float4 b0 = pb[0], b1 = pb[1];
            float cut = cut_l[r], sc = isv_l[r];
            ushort bw[8];
            bw[0]=f2bf(b0.x >= cut ? b0.x * sc : 0.f);
            bw[1]=f2bf(b0.y >= cut ? b0.y * sc : 0.f);
            bw[2]=f2bf(b0.z >= cut ? b0.z * sc : 0.f);
            bw[3]=f2bf(b0.w >= cut ? b0.w * sc : 0.f);
            bw[4]=f2bf(b1.x >= cut ? b1.x * sc : 0.f);
            bw[5]=f2bf(b1.y >= cut ? b1.y * sc : 0.f);
            bw[6]=f2bf(b1.z >= cut ? b1.z * sc : 0.f);
            bw[7]=f2bf(b1.w >= cut ? b1.w * sc : 0.f);
            *(s16x8*)&Bl[r * 72 + c8] = *(const s16x8*)bw;
        }
        __syncthreads();
#pragma unroll
        for (int kk = 0; kk < 2; ++kk) {
            s16x8 af[4], bf[4];
#pragma unroll
            for (int i = 0; i < 4; ++i)
                af[i] = *(const s16x8*)&Al[(wr + i * 16 + lr) * 72 + kk * 32 + lg * 8];
#pragma unroll
            for (int j = 0; j < 4; ++j)
                bf[j] = *(const s16x8*)&Bl[(wc + j * 16 + lr) * 72 + kk * 32 + lg * 8];
#pragma unroll
            for (int i = 0; i < 4; ++i)
#pragma unroll
                for (int j = 0; j < 4; ++j)
                    acc[i][j] = __builtin_amdgcn_mfma_f32_16x16x32_bf16(af[i], bf[j], acc[i][j], 0, 0, 0);
        }
    }

#pragma unroll
    for (int i = 0; i < 4; ++i)
#pragma unroll
        for (int j = 0; j < 4; ++j)
#pragma unroll
            for (int reg = 0; reg < 4; ++reg) {
                int c = c0 + wr + i * 16 + lg * 4 + reg;
                int t = t0 + wc + j * 16 + lr;
                out0[((size_t)(b * C_ + c)) * T_ + t] = acc[i][j][reg] + Xb[(size_t)c * T_ + t];
            }
}

// ---------------------------------------------------------------------------
extern "C" void kernel_launch(void* const* d_in, const int* in_sizes, int n_in,
                              void* d_out, int out_size, void* d_ws, size_t ws_size,
                              hipStream_t stream) {
    const float* x = (const float*)d_in[0];
    float* out0 = (float*)d_out;                              // (B,C,T)
    float* sim  = out0 + (size_t)B_ * C_ * T_;                // (B,T,T)

    ushort* xt = (ushort*)d_out;   // scratch in out0 region until out_mfma

    float* invn   = (float*)d_ws;                             // B*T
    float* cutoff = invn + B_ * T_;                           // B*T
    float* isv    = cutoff + B_ * T_;                         // B*T

    norm_kernel  <<<dim3(T_ / 256, B_),           256, 0, stream>>>(x, invn);
    xt_kernel    <<<dim3(T_ / 64, C_ / 64, B_),   256, 0, stream>>>(x, invn, xt);
    sim_mfma     <<<dim3(T_ / 128, T_ / 128, B_), 256, 0, stream>>>(xt, sim);
    select_kernel<<<dim3(B_ * T_ / 4),            256, 0, stream>>>(sim, cutoff, isv);
    out_mfma     <<<dim3(T_ / 128, C_ / 128, B_), 256, 0, stream>>>(x, sim, cutoff, isv, out0);
}